// Round 6
// baseline (229.575 us; speedup 1.0000x reference)
//
#include <hip/hip_runtime.h>
#include <math.h>

// Problem shape (from reference setup_inputs): B=4096, D=2048, C=1000, N=C+B=5096.
#define D_DIM 2048
#define GAP_TAU 0.02f   // per-logit |fp16_approx - fp32_exact| bound (>20 sigma)

typedef _Float16 f16;
typedef f16 f16x8 __attribute__((ext_vector_type(8)));
typedef float f32x4 __attribute__((ext_vector_type(4)));

__device__ __forceinline__ const float* support_row(int i, const float* __restrict__ W,
                                                    const float* __restrict__ z, int C) {
  return (i < C) ? (W + (size_t)i * D_DIM) : (z + (size_t)(i - C) * D_DIM);
}

// async global->LDS, 16B per lane. LDS dest = wave-uniform base + lane*16.
__device__ __forceinline__ void async_ld16(const f16* g, f16* l) {
  __builtin_amdgcn_global_load_lds((const __attribute__((address_space(1))) void*)g,
                                   (__attribute__((address_space(3))) void*)l, 16, 0, 0);
}

// ---------------------------------------------------------------------------
// prep: suph[i][:] = f16(support_row(i)) (zeros for pad rows); norms[i] = ||row||.
// One wave per row (4 rows/block), shuffle-only reduction.
// ---------------------------------------------------------------------------
__global__ __launch_bounds__(256) void prep_kernel(const float* __restrict__ z,
                                                   const float* __restrict__ W,
                                                   int C, int Nsup,
                                                   f16* __restrict__ suph,
                                                   float* __restrict__ norms) {
  const int wave = threadIdx.x >> 6;
  const int lane = threadIdx.x & 63;
  const int i = blockIdx.x * 4 + wave;
  f16* dst = suph + (size_t)i * D_DIM;
  if (i >= Nsup) {
    f16x8 zz = {0, 0, 0, 0, 0, 0, 0, 0};
#pragma unroll
    for (int p = 0; p < 4; p++) *(f16x8*)(dst + p * 512 + lane * 8) = zz;
    return;
  }
  const float* src = support_row(i, W, z, C);
  float ss = 0.f;
#pragma unroll
  for (int p = 0; p < 4; p++) {
    const int off = p * 512 + lane * 8;
    const float4 a = *(const float4*)(src + off);
    const float4 b = *(const float4*)(src + off + 4);
    f16x8 v;
    v[0] = (f16)a.x; v[1] = (f16)a.y; v[2] = (f16)a.z; v[3] = (f16)a.w;
    v[4] = (f16)b.x; v[5] = (f16)b.y; v[6] = (f16)b.z; v[7] = (f16)b.w;
    *(f16x8*)(dst + off) = v;
    ss = fmaf(a.x, a.x, ss); ss = fmaf(a.y, a.y, ss);
    ss = fmaf(a.z, a.z, ss); ss = fmaf(a.w, a.w, ss);
    ss = fmaf(b.x, b.x, ss); ss = fmaf(b.y, b.y, ss);
    ss = fmaf(b.z, b.z, ss); ss = fmaf(b.w, b.w, ss);
  }
#pragma unroll
  for (int s = 1; s < 64; s <<= 1) ss += __shfl_xor(ss, s);
  if (lane == 0) norms[i] = sqrtf(ss);
}

// ---------------------------------------------------------------------------
// Shared GEMM core: 128x64 tile, BK=32, 256 thr = 4 waves, wave = 32 rows x
// 64 cols (MFMA tiles i in {0,1}, j in {0..3}, 16x16x32). global_load_lds
// width=16 staging, 16B-chunk XOR swizzle key (row>>1)&3 (conflict-free).
// A/B padded to tile multiples; all loads unguarded.
//
// STAGING CONTRACT (round-5 bug): global_load_lds writes LDS chunk
// (wave-uniform base)/16 + lane. The global source index MUST be derived from
// that same chunk id. A base = (wave*2+s)*512 f16 -> chunk (wave*2+s)*64+lane.
// ---------------------------------------------------------------------------
#define TM1 128
#define TN1 64

struct GemmAcc {
  f32x4 acc[2][4];
};

__device__ __forceinline__ void gemm_core(const f16* __restrict__ A,
                                          const f16* __restrict__ Bm,
                                          int K, int row0, int col0, GemmAcc& g) {
  __shared__ __align__(16) f16 As[TM1 * 32];  // 8 KB
  __shared__ __align__(16) f16 Bs[TN1 * 32];  // 4 KB

  const int tid = threadIdx.x;
  const int wave = tid >> 6;
  const int lane = tid & 63;
  const int quad = lane >> 4;
  const int lr = lane & 15;
  const int wr = wave * 32;

  // A staging: 512 chunks -> 2 instr/thread; B: 256 chunks -> 1 instr/thread
  const f16* ag[2];
  f16* al[2];
#pragma unroll
  for (int s = 0; s < 2; s++) {
    const int i = (wave * 2 + s) * 64 + lane;  // == LDS chunk id (FIX: was s*256+tid)
    const int row = i >> 2;
    const int cg = (i & 3) ^ ((row >> 1) & 3);
    ag[s] = A + (size_t)(row0 + row) * K + cg * 8;
    al[s] = As + (wave * 2 + s) * 512;
  }
  const f16* bg;
  f16* bl;
  {
    const int row = tid >> 2;                  // chunk id == tid == wave*64+lane
    const int cg = (tid & 3) ^ ((row >> 1) & 3);
    bg = Bm + (size_t)(col0 + row) * K + cg * 8;
    bl = Bs + wave * 512;
  }

  int aoff[2], boff[4];
#pragma unroll
  for (int i = 0; i < 2; i++) {
    const int ra = wr + i * 16 + lr;
    aoff[i] = ra * 32 + (quad ^ ((ra >> 1) & 3)) * 8;
  }
#pragma unroll
  for (int j = 0; j < 4; j++) {
    const int rb = j * 16 + lr;
    boff[j] = rb * 32 + (quad ^ ((rb >> 1) & 3)) * 8;
  }

#pragma unroll
  for (int i = 0; i < 2; i++)
#pragma unroll
    for (int j = 0; j < 4; j++) {
      g.acc[i][j][0] = 0.f; g.acc[i][j][1] = 0.f;
      g.acc[i][j][2] = 0.f; g.acc[i][j][3] = 0.f;
    }

  for (int k0 = 0; k0 < K; k0 += 32) {
    async_ld16(ag[0] + k0, al[0]);
    async_ld16(ag[1] + k0, al[1]);
    async_ld16(bg + k0, bl);
    __syncthreads();

    f16x8 af[2], bf[4];
#pragma unroll
    for (int i = 0; i < 2; i++) af[i] = *(const f16x8*)(As + aoff[i]);
#pragma unroll
    for (int j = 0; j < 4; j++) bf[j] = *(const f16x8*)(Bs + boff[j]);
#pragma unroll
    for (int i = 0; i < 2; i++)
#pragma unroll
      for (int j = 0; j < 4; j++)
        g.acc[i][j] = __builtin_amdgcn_mfma_f32_16x16x32_f16(af[i], bf[j], g.acc[i][j], 0, 0, 0);
    __syncthreads();
  }
}

// ---------------------------------------------------------------------------
// gemm1_stats: logits = supports @ W^T with fused per-segment row stats.
// Writes logits[Mpad x 1024] (for ambiguity repair) and Sseg[row][16 segs][8]:
// {m1, m2, bitcast(i1), s1, s2} with s1/s2 online-softmax partials rel. m1.
// Cols >= C (garbage from padded B rows) are masked out of the stats.
// ---------------------------------------------------------------------------
__global__ __launch_bounds__(256) void gemm1_stats(const f16* __restrict__ A,
                                                   const f16* __restrict__ Bm,
                                                   float* __restrict__ logits,
                                                   float* __restrict__ Sseg,
                                                   int K, int C, int ldc) {
  GemmAcc g;
  const int row0 = blockIdx.x * TM1;
  const int col0 = blockIdx.y * TN1;
  gemm_core(A, Bm, K, row0, col0, g);

  const int lane = threadIdx.x & 63;
  const int wave = threadIdx.x >> 6;
  const int quad = lane >> 4;
  const int lr = lane & 15;
  const int wr = wave * 32;

  // 1) raw logits (repair path reads ambiguous rows only)
#pragma unroll
  for (int i = 0; i < 2; i++)
#pragma unroll
    for (int reg = 0; reg < 4; reg++) {
      const int r = row0 + wr + i * 16 + quad * 4 + reg;
#pragma unroll
      for (int j = 0; j < 4; j++) {
        const int c = col0 + j * 16 + lr;
        logits[(size_t)r * ldc + c] = g.acc[i][j][reg];
      }
    }

  // 2) per-(row, segment) stats; segment = blockIdx.y (64 cols)
#pragma unroll
  for (int i = 0; i < 2; i++) {
#pragma unroll
    for (int reg = 0; reg < 4; reg++) {
      float m1 = -3.0e38f, m2 = -3.0e38f;
      int i1 = 0x7fffffff;
#pragma unroll
      for (int j = 0; j < 4; j++) {
        const int c = col0 + j * 16 + lr;
        const float v = (c < C) ? g.acc[i][j][reg] : -3.0e38f;
        if (v > m1) { m2 = m1; m1 = v; i1 = c; }
        else if (v > m2) { m2 = v; }   // v == m1 lands here -> gap 0
      }
      // merge over the 16 lanes (lr) of this row group
#pragma unroll
      for (int s = 1; s < 16; s <<= 1) {
        const float om1 = __shfl_xor(m1, s);
        const float om2 = __shfl_xor(m2, s);
        const int oi1 = __shfl_xor(i1, s);
        if (om1 > m1) { m2 = fmaxf(m1, om2); m1 = om1; i1 = oi1; }
        else if (om1 < m1) { m2 = fmaxf(m2, om1); }
        else { i1 = min(i1, oi1); m2 = m1; }
      }
      // softmax partials rel. segment max m1
      float s1 = 0.f, s2 = 0.f;
#pragma unroll
      for (int j = 0; j < 4; j++) {
        const int c = col0 + j * 16 + lr;
        if (c < C) {
          const float d = g.acc[i][j][reg] - m1;
          const float e = __expf(d);
          s1 += e;
          s2 = fmaf(d, e, s2);
        }
      }
#pragma unroll
      for (int s = 1; s < 16; s <<= 1) {
        s1 += __shfl_xor(s1, s);
        s2 += __shfl_xor(s2, s);
      }
      if (lr == 0) {
        const int r = row0 + wr + i * 16 + quad * 4 + reg;
        float* sp = Sseg + ((size_t)r * 16 + blockIdx.y) * 8;
        float4 w0;
        w0.x = m1; w0.y = m2; w0.z = __int_as_float(i1); w0.w = s1;
        *(float4*)sp = w0;
        sp[4] = s2;
      }
    }
  }
}

// ---------------------------------------------------------------------------
// merge_repair: one wave per row (4 rows/block). Merge 16 segment stats
// (online-softmax rescale + top-2/argmax with lowest-index ties) -> ent, yhat.
// Ambiguous rows (gap <= 2*TAU) get exact fp32 argmax over candidate classes
// (approx logit >= max - 2*TAU — provably contains the true argmax).
// ---------------------------------------------------------------------------
__global__ __launch_bounds__(256) void merge_repair(const float* __restrict__ Sseg,
                                                    const float* __restrict__ logits,
                                                    int ldl, int Cc,
                                                    const float* __restrict__ z,
                                                    const float* __restrict__ W,
                                                    int Nsup,
                                                    float* __restrict__ ent,
                                                    int* __restrict__ yhat) {
  const int wave = threadIdx.x >> 6;
  const int lane = threadIdx.x & 63;
  const int r = blockIdx.x * 4 + wave;
  if (r >= Nsup) return;

  // every lane loads segment (lane & 15); merge happens within 16-lane groups
  const float* sp = Sseg + ((size_t)r * 16 + (lane & 15)) * 8;
  const float4 w0 = *(const float4*)sp;
  float m = w0.x, g2 = w0.y, s1 = w0.w, s2 = sp[4];
  int idx = __float_as_int(w0.z);

#pragma unroll
  for (int s = 1; s < 16; s <<= 1) {
    const float om = __shfl_xor(m, s);
    const float og2 = __shfl_xor(g2, s);
    const int oi = __shfl_xor(idx, s);
    const float os1 = __shfl_xor(s1, s);
    const float os2 = __shfl_xor(s2, s);
    const float M = fmaxf(m, om);
    const float a = __expf(m - M);
    const float b = __expf(om - M);
    const float ns1 = a * s1 + b * os1;
    const float ns2 = a * fmaf(m - M, s1, s2) + b * fmaf(om - M, os1, os2);
    if (om > m) { g2 = fmaxf(m, og2); m = om; idx = oi; }
    else if (om < m) { g2 = fmaxf(g2, om); }
    else { idx = min(idx, oi); g2 = m; }
    s1 = ns1; s2 = ns2;
  }
  // broadcast merged values wave-wide (merge valid within each 16-lane group)
  const float M1 = __shfl(m, 0);
  const float M2 = __shfl(g2, 0);
  const float S1 = __shfl(s1, 0);
  const float S2 = __shfl(s2, 0);
  int I1 = __shfl(idx, 0);

  if (M1 - M2 <= 2.0f * GAP_TAU) {
    const float thresh = M1 - 2.0f * GAP_TAU;
    const float* rowl = logits + (size_t)r * ldl;
    const float* srow = support_row(r, W, z, Cc);
    float best = -3.0e38f;
    int bi = 0x7fffffff;
#pragma unroll
    for (int j = 0; j < 16; j++) {
      const int c = lane + j * 64;
      const float v = (c < Cc) ? rowl[c] : -3.0e38f;
      unsigned long long mask = __ballot(v >= thresh);
      while (mask) {
        const int src = __ffsll((long long)mask) - 1;
        mask &= mask - 1;
        const int cc = src + j * 64;
        const float* wrow = W + (size_t)cc * D_DIM;
        float sdot = 0.f;
        for (int d = lane; d < D_DIM; d += 64) sdot = fmaf(srow[d], wrow[d], sdot);
#pragma unroll
        for (int t = 1; t < 64; t <<= 1) sdot += __shfl_xor(sdot, t);
        if (sdot > best || (sdot == best && cc < bi)) { best = sdot; bi = cc; }
      }
    }
    I1 = bi;
  }

  if (lane == 0) {
    ent[r] = logf(S1) - S2 / S1;
    yhat[r] = I1;
  }
}

// ---------------------------------------------------------------------------
// accum: per class — gather members into LDS, top-K by entropy if count > K
// (never in practice: mean ~5, K=100), sum normalized rows, column-normalize,
// write f16 weights row. Pad classes write zeros.
// ---------------------------------------------------------------------------
#define MAXLIST 1024

__global__ __launch_bounds__(256) void accum_kernel(const float* __restrict__ z,
                                                    const float* __restrict__ W,
                                                    int C, int Nsup,
                                                    const int* __restrict__ yhat,
                                                    const float* __restrict__ ent,
                                                    const float* __restrict__ norms,
                                                    const int* __restrict__ Kp,
                                                    f16* __restrict__ wh) {
  const int c = blockIdx.x;
  const int t = threadIdx.x;
  f16* dst = wh + (size_t)c * D_DIM + t * 8;
  if (c >= C) {
    f16x8 zz = {0, 0, 0, 0, 0, 0, 0, 0};
    *(f16x8*)dst = zz;
    return;
  }

  __shared__ int list[MAXLIST];
  __shared__ unsigned char sel[MAXLIST];
  __shared__ int cnt;
  __shared__ float red[256];
  if (t == 0) cnt = 0;
  __syncthreads();
  for (int i = t; i < Nsup; i += 256) {
    if (yhat[i] == c) {
      const int p = atomicAdd(&cnt, 1);
      if (p < MAXLIST) list[p] = i;
    }
  }
  __syncthreads();
  const int K = *Kp;
  const int n = min(cnt, MAXLIST);
  if (cnt <= K) {
    for (int j = t; j < n; j += 256) sel[j] = 1;
  } else {
    for (int j = t; j < n; j += 256) {
      const int si = list[j];
      const float ei = ent[si];
      int rank = 0;
      for (int l = 0; l < n; l++) {
        const int sl = list[l];
        const float el = ent[sl];
        rank += (el < ei || (el == ei && sl < si)) ? 1 : 0;
      }
      sel[j] = (rank < K) ? 1 : 0;
    }
  }
  __syncthreads();

  float a[8];
#pragma unroll
  for (int q = 0; q < 8; q++) a[q] = 0.f;
  for (int j = 0; j < n; j++) {
    if (!sel[j]) continue;
    const int si = list[j];
    const float* row = support_row(si, W, z, C) + t * 8;
    const float inv = 1.0f / fmaxf(norms[si], 1e-12f);
    const float4 p0 = *(const float4*)row;
    const float4 p1 = *(const float4*)(row + 4);
    a[0] = fmaf(p0.x, inv, a[0]); a[1] = fmaf(p0.y, inv, a[1]);
    a[2] = fmaf(p0.z, inv, a[2]); a[3] = fmaf(p0.w, inv, a[3]);
    a[4] = fmaf(p1.x, inv, a[4]); a[5] = fmaf(p1.y, inv, a[5]);
    a[6] = fmaf(p1.z, inv, a[6]); a[7] = fmaf(p1.w, inv, a[7]);
  }

  float ss = 0.f;
#pragma unroll
  for (int q = 0; q < 8; q++) ss = fmaf(a[q], a[q], ss);
  red[t] = ss;
  __syncthreads();
  for (int k = 128; k > 0; k >>= 1) {
    if (t < k) red[t] += red[t + k];
    __syncthreads();
  }
  const float invn = 1.0f / fmaxf(sqrtf(red[0]), 1e-12f);
  f16x8 o;
#pragma unroll
  for (int q = 0; q < 8; q++) o[q] = (f16)(a[q] * invn);
  *(f16x8*)dst = o;
}

// ---------------------------------------------------------------------------
// gemm2_out: out[B, C] = z @ weights^T, written directly (col-predicated).
// ---------------------------------------------------------------------------
__global__ __launch_bounds__(256) void gemm2_out(const f16* __restrict__ A,
                                                 const f16* __restrict__ Bm,
                                                 float* __restrict__ out,
                                                 int K, int C) {
  GemmAcc g;
  const int row0 = blockIdx.x * TM1;
  const int col0 = blockIdx.y * TN1;
  gemm_core(A, Bm, K, row0, col0, g);

  const int lane = threadIdx.x & 63;
  const int wave = threadIdx.x >> 6;
  const int quad = lane >> 4;
  const int lr = lane & 15;
  const int wr = wave * 32;

#pragma unroll
  for (int i = 0; i < 2; i++)
#pragma unroll
    for (int reg = 0; reg < 4; reg++) {
      const int r = row0 + wr + i * 16 + quad * 4 + reg;
#pragma unroll
      for (int j = 0; j < 4; j++) {
        const int c = col0 + j * 16 + lr;
        if (c < C) out[(size_t)r * C + c] = g.acc[i][j][reg];
      }
    }
}

// ---------------------------------------------------------------------------
// Launch
// ---------------------------------------------------------------------------
extern "C" void kernel_launch(void* const* d_in, const int* in_sizes, int n_in,
                              void* d_out, int out_size, void* d_ws, size_t ws_size,
                              hipStream_t stream) {
  const float* z = (const float*)d_in[0];
  const float* W = (const float*)d_in[1];
  const int* Kp = (const int*)d_in[2];

  const int D = D_DIM;
  const int B = in_sizes[0] / D;   // 4096
  const int C = in_sizes[1] / D;   // 1000
  const int Nsup = C + B;          // 5096
  const int Mpad = (Nsup + TM1 - 1) / TM1 * TM1;  // 5120
  const int Npad = (C + TN1 - 1) / TN1 * TN1;     // 1024

  char* ws = (char*)d_ws;
  size_t off = 0;
  auto alloc = [&](size_t bytes) -> void* {
    void* p = ws + off;
    off += (bytes + 255) & ~(size_t)255;
    return p;
  };

  f16*   suph   = (f16*)alloc((size_t)Mpad * D * sizeof(f16));          // ~21.0 MB
  f16*   wh     = (f16*)alloc((size_t)Npad * D * sizeof(f16));          // ~4.2 MB
  float* logits = (float*)alloc((size_t)Mpad * Npad * sizeof(float));   // ~21.0 MB
  float* Sseg   = (float*)alloc((size_t)Mpad * 16 * 8 * sizeof(float)); // ~2.6 MB
  float* ent    = (float*)alloc((size_t)Nsup * sizeof(float));
  int*   yhat   = (int*)alloc((size_t)Nsup * sizeof(int));
  float* norms  = (float*)alloc((size_t)Nsup * sizeof(float));
  (void)ws_size;

  // 1) f16 support matrix (padded) + norms
  prep_kernel<<<Mpad / 4, 256, 0, stream>>>(z, W, C, Nsup, suph, norms);

  // 2) logits + fused per-segment row stats (640 blocks)
  {
    dim3 grid(Mpad / TM1, Npad / TN1);
    gemm1_stats<<<grid, 256, 0, stream>>>(suph, suph, logits, Sseg, D, C, Npad);
  }

  // 3) segment merge (online softmax) + exact argmax repair for ambiguous rows
  merge_repair<<<(Nsup + 3) / 4, 256, 0, stream>>>(Sseg, logits, Npad, C, z, W,
                                                   Nsup, ent, yhat);

  // 4) per-class gather/select/accumulate/normalize -> wh[Npad, D] f16
  accum_kernel<<<Npad, 256, 0, stream>>>(z, W, C, Nsup, yhat, ent, norms, Kp, wh);

  // 5) out[B, C] = z @ weights^T, direct store (512 blocks)
  {
    dim3 grid(B / TM1, Npad / TN1);
    gemm2_out<<<grid, 256, 0, stream>>>(suph + (size_t)C * D, wh, (float*)d_out, D, C);
  }
}

// Round 7
// 200.316 us; speedup vs baseline: 1.1461x; 1.1461x over previous
//
#include <hip/hip_runtime.h>
#include <math.h>

// Problem shape (from reference setup_inputs): B=4096, D=2048, C=1000, N=C+B=5096.
#define D_DIM 2048
#define GAP_TAU 0.02f   // per-logit |approx - fp32_exact| bound (>8 sigma incl. split-add)

typedef _Float16 f16;
typedef f16 f16x8 __attribute__((ext_vector_type(8)));
typedef float f32x4 __attribute__((ext_vector_type(4)));

__device__ __forceinline__ const float* support_row(int i, const float* __restrict__ W,
                                                    const float* __restrict__ z, int C) {
  return (i < C) ? (W + (size_t)i * D_DIM) : (z + (size_t)(i - C) * D_DIM);
}

// async global->LDS, 16B per lane. LDS dest = wave-uniform base + lane*16.
__device__ __forceinline__ void async_ld16(const f16* g, f16* l) {
  __builtin_amdgcn_global_load_lds((const __attribute__((address_space(1))) void*)g,
                                   (__attribute__((address_space(3))) void*)l, 16, 0, 0);
}

// ---------------------------------------------------------------------------
// prep: suph[i][:] = f16(support_row(i)) (zeros for pad rows); norms[i] = ||row||.
// One wave per row (4 rows/block), shuffle-only reduction.
// ---------------------------------------------------------------------------
__global__ __launch_bounds__(256) void prep_kernel(const float* __restrict__ z,
                                                   const float* __restrict__ W,
                                                   int C, int Nsup,
                                                   f16* __restrict__ suph,
                                                   float* __restrict__ norms) {
  const int wave = threadIdx.x >> 6;
  const int lane = threadIdx.x & 63;
  const int i = blockIdx.x * 4 + wave;
  f16* dst = suph + (size_t)i * D_DIM;
  if (i >= Nsup) {
    f16x8 zz = {0, 0, 0, 0, 0, 0, 0, 0};
#pragma unroll
    for (int p = 0; p < 4; p++) *(f16x8*)(dst + p * 512 + lane * 8) = zz;
    return;
  }
  const float* src = support_row(i, W, z, C);
  float ss = 0.f;
#pragma unroll
  for (int p = 0; p < 4; p++) {
    const int off = p * 512 + lane * 8;
    const float4 a = *(const float4*)(src + off);
    const float4 b = *(const float4*)(src + off + 4);
    f16x8 v;
    v[0] = (f16)a.x; v[1] = (f16)a.y; v[2] = (f16)a.z; v[3] = (f16)a.w;
    v[4] = (f16)b.x; v[5] = (f16)b.y; v[6] = (f16)b.z; v[7] = (f16)b.w;
    *(f16x8*)(dst + off) = v;
    ss = fmaf(a.x, a.x, ss); ss = fmaf(a.y, a.y, ss);
    ss = fmaf(a.z, a.z, ss); ss = fmaf(a.w, a.w, ss);
    ss = fmaf(b.x, b.x, ss); ss = fmaf(b.y, b.y, ss);
    ss = fmaf(b.z, b.z, ss); ss = fmaf(b.w, b.w, ss);
  }
#pragma unroll
  for (int s = 1; s < 64; s <<= 1) ss += __shfl_xor(ss, s);
  if (lane == 0) norms[i] = sqrtf(ss);
}

// ---------------------------------------------------------------------------
// fp16 MFMA GEMM, split-K=2 via blockIdx.z (R4-proven, 43 us): P[kz] =
// A[:, kz*Ks:(kz+1)*Ks] @ B^T. 128x128 tile, BK=32, 256 thr = 4 waves (2x2),
// wave = 64x64 = 4x4 MFMA 16x16x32. global_load_lds width=16 staging,
// 16B-chunk XOR swizzle key (row>>1)&3 (conflict-free). A/B padded to x128
// rows; stores unpredicated into padded partial buffers.
// ---------------------------------------------------------------------------
#define TM 128
#define TN 128

__global__ __launch_bounds__(256) void gemm_f16(const f16* __restrict__ A,
                                                const f16* __restrict__ B,
                                                float* __restrict__ P,
                                                int K, int Ks, long partStride, int ldc) {
  __shared__ __align__(16) f16 As[TM * 32];
  __shared__ __align__(16) f16 Bs[TN * 32];

  const int tid = threadIdx.x;
  const int wave = tid >> 6;
  const int lane = tid & 63;
  const int quad = lane >> 4;
  const int lr = lane & 15;
  const int row0 = blockIdx.x * TM;
  const int col0 = blockIdx.y * TN;
  const int kz = blockIdx.z;
  const int kbase = kz * Ks;
  const int wr = (wave >> 1) * 64;
  const int wc = (wave & 1) * 64;

  const f16* ag[2];
  const f16* bg[2];
  f16* al[2];
  f16* bl[2];
#pragma unroll
  for (int s = 0; s < 2; s++) {
    const int i = (wave * 2 + s) * 64 + lane;   // == LDS chunk id (staging contract)
    const int row = i >> 2;
    const int cg = (i & 3) ^ ((row >> 1) & 3);
    ag[s] = A + (size_t)(row0 + row) * K + kbase + cg * 8;
    bg[s] = B + (size_t)(col0 + row) * K + kbase + cg * 8;
    al[s] = As + (wave * 2 + s) * 512;
    bl[s] = Bs + (wave * 2 + s) * 512;
  }

  int aoff[4], boff[4];
#pragma unroll
  for (int tq = 0; tq < 4; tq++) {
    const int ra = wr + tq * 16 + lr;
    aoff[tq] = ra * 32 + (quad ^ ((ra >> 1) & 3)) * 8;
    const int rb = wc + tq * 16 + lr;
    boff[tq] = rb * 32 + (quad ^ ((rb >> 1) & 3)) * 8;
  }

  f32x4 acc[4][4];
#pragma unroll
  for (int i = 0; i < 4; i++)
#pragma unroll
    for (int j = 0; j < 4; j++) {
      acc[i][j][0] = 0.f; acc[i][j][1] = 0.f; acc[i][j][2] = 0.f; acc[i][j][3] = 0.f;
    }

  for (int k0 = 0; k0 < Ks; k0 += 32) {
#pragma unroll
    for (int s = 0; s < 2; s++) {
      async_ld16(ag[s] + k0, al[s]);
      async_ld16(bg[s] + k0, bl[s]);
    }
    __syncthreads();

    f16x8 af[4], bf[4];
#pragma unroll
    for (int i = 0; i < 4; i++) af[i] = *(const f16x8*)(As + aoff[i]);
#pragma unroll
    for (int i = 0; i < 4; i++) bf[i] = *(const f16x8*)(Bs + boff[i]);
#pragma unroll
    for (int i = 0; i < 4; i++)
#pragma unroll
      for (int j = 0; j < 4; j++)
        acc[i][j] = __builtin_amdgcn_mfma_f32_16x16x32_f16(af[i], bf[j], acc[i][j], 0, 0, 0);
    __syncthreads();
  }

  float* out = P + (size_t)kz * partStride;
#pragma unroll
  for (int i = 0; i < 4; i++)
#pragma unroll
    for (int reg = 0; reg < 4; reg++) {
      const int r = row0 + wr + i * 16 + quad * 4 + reg;
#pragma unroll
      for (int j = 0; j < 4; j++) {
        const int c = col0 + wc + j * 16 + lr;
        out[(size_t)r * ldc + c] = acc[i][j][reg];
      }
    }
}

// ---------------------------------------------------------------------------
// row_stats (block-per-row): logits row = P0 + P1 read as two coalesced
// float4 per thread (thread t owns cols t*4..t*4+3 of 1024). Argmax
// (lowest-index ties) + top-2 gap + entropy; ambiguous rows (gap <= 2*TAU)
// repaired with exact fp32 dots over candidate classes (approx logit >=
// max - 2*TAU — provably contains the true argmax).
// ---------------------------------------------------------------------------
__global__ __launch_bounds__(256) void row_stats(const float* __restrict__ P,
                                                 long partStride, int ldp, int Cc,
                                                 const float* __restrict__ z,
                                                 const float* __restrict__ W,
                                                 float* __restrict__ ent,
                                                 int* __restrict__ yhat) {
  const int r = blockIdx.x;
  const int t = threadIdx.x;
  const int wave = t >> 6;
  const int lane = t & 63;
  const float* r0 = P + (size_t)r * ldp;
  const float* r1 = r0 + partStride;

  const int c0 = t * 4;
  const float4 a = *(const float4*)(r0 + c0);
  const float4 b = *(const float4*)(r1 + c0);
  float v[4] = {a.x + b.x, a.y + b.y, a.z + b.z, a.w + b.w};
#pragma unroll
  for (int k = 0; k < 4; k++)
    if (c0 + k >= Cc) v[k] = -3.0e38f;

  // per-thread top-2 (+ lowest argmax idx; ascending k -> first hit wins)
  float m1 = -3.0e38f, m2 = -3.0e38f;
  int i1 = 0x7fffffff;
#pragma unroll
  for (int k = 0; k < 4; k++) {
    if (v[k] > m1) { m2 = m1; m1 = v[k]; i1 = c0 + k; }
    else if (v[k] > m2) { m2 = v[k]; }   // v[k]==m1 lands here -> m2=m1 (gap 0)
  }
  // wave merge
#pragma unroll
  for (int s = 1; s < 64; s <<= 1) {
    const float om1 = __shfl_xor(m1, s);
    const float om2 = __shfl_xor(m2, s);
    const int oi1 = __shfl_xor(i1, s);
    if (om1 > m1) { m2 = fmaxf(m1, om2); m1 = om1; i1 = oi1; }
    else if (om1 < m1) { m2 = fmaxf(m2, om1); }
    else { i1 = min(i1, oi1); m2 = m1; }
  }
  // cross-wave merge via LDS
  __shared__ float sm1[4], sm2[4];
  __shared__ int si[4];
  __shared__ float bc[4];   // M1, M2, S1, S2
  __shared__ int bidx;
  if (lane == 0) { sm1[wave] = m1; sm2[wave] = m2; si[wave] = i1; }
  __syncthreads();
  if (t == 0) {
    float M1 = sm1[0], M2 = sm2[0];
    int I = si[0];
#pragma unroll
    for (int w = 1; w < 4; w++) {
      const float o1 = sm1[w], o2 = sm2[w];
      const int oi = si[w];
      if (o1 > M1) { M2 = fmaxf(M1, o2); M1 = o1; I = oi; }
      else if (o1 < M1) { M2 = fmaxf(M2, o1); }
      else { I = min(I, oi); M2 = M1; }
    }
    bc[0] = M1; bc[1] = M2; bidx = I;
  }
  __syncthreads();
  const float M1 = bc[0];
  const float M2 = bc[1];
  int I1 = bidx;

  // entropy sums rel. M1 (consumed only if a class exceeds K members)
  float s1 = 0.f, s2 = 0.f;
#pragma unroll
  for (int k = 0; k < 4; k++) {
    if (c0 + k < Cc) {
      const float d = v[k] - M1;
      const float e = __expf(d);
      s1 += e;
      s2 = fmaf(d, e, s2);
    }
  }
#pragma unroll
  for (int s = 1; s < 64; s <<= 1) {
    s1 += __shfl_xor(s1, s);
    s2 += __shfl_xor(s2, s);
  }
  if (lane == 0) { sm1[wave] = s1; sm2[wave] = s2; }
  __syncthreads();
  if (t == 0) {
    bc[2] = sm1[0] + sm1[1] + sm1[2] + sm1[3];
    bc[3] = sm2[0] + sm2[1] + sm2[2] + sm2[3];
  }

  // ambiguous-argmax repair with exact fp32 dots (rare: ~5% of rows)
  if (M1 - M2 <= 2.0f * GAP_TAU) {
    __shared__ int cand[64];
    __shared__ int ncand;
    __shared__ float red[256];
    if (t == 0) ncand = 0;
    __syncthreads();
    const float thresh = M1 - 2.0f * GAP_TAU;
#pragma unroll
    for (int k = 0; k < 4; k++) {
      if (c0 + k < Cc && v[k] >= thresh) {
        const int p = atomicAdd(&ncand, 1);
        if (p < 64) cand[p] = c0 + k;
      }
    }
    __syncthreads();
    const bool overflow = (ncand > 64);
    const int nc = overflow ? Cc : ncand;
    const float* srow = support_row(r, W, z, Cc);
    float best = -3.0e38f;
    int bi = 0x7fffffff;
    for (int j = 0; j < nc; j++) {
      const int c = overflow ? j : cand[j];
      const float* wrow = W + (size_t)c * D_DIM;
      float s = 0.f;
      for (int d = t; d < D_DIM; d += 256) s = fmaf(srow[d], wrow[d], s);
      red[t] = s;
      __syncthreads();
      for (int k = 128; k > 0; k >>= 1) {
        if (t < k) red[t] += red[t + k];
        __syncthreads();
      }
      const float val = red[0];
      __syncthreads();
      if (val > best || (val == best && c < bi)) { best = val; bi = c; }
    }
    I1 = bi;
  }
  __syncthreads();

  if (t == 0) {
    const float S1 = bc[2], S2 = bc[3];
    ent[r] = logf(S1) - S2 / S1;
    yhat[r] = I1;
  }
}

// ---------------------------------------------------------------------------
// accum: per class — gather members into LDS, top-K by entropy if count > K
// (never in practice: mean ~5, K=100), sum normalized rows, column-normalize,
// write f16 weights row. Pad classes write zeros. Thread t owns dims t*8..+7.
// ---------------------------------------------------------------------------
#define MAXLIST 1024

__global__ __launch_bounds__(256) void accum_kernel(const float* __restrict__ z,
                                                    const float* __restrict__ W,
                                                    int C, int Nsup,
                                                    const int* __restrict__ yhat,
                                                    const float* __restrict__ ent,
                                                    const float* __restrict__ norms,
                                                    const int* __restrict__ Kp,
                                                    f16* __restrict__ wh) {
  const int c = blockIdx.x;
  const int t = threadIdx.x;
  f16* dst = wh + (size_t)c * D_DIM + t * 8;
  if (c >= C) {
    f16x8 zz = {0, 0, 0, 0, 0, 0, 0, 0};
    *(f16x8*)dst = zz;
    return;
  }

  __shared__ int list[MAXLIST];
  __shared__ unsigned char sel[MAXLIST];
  __shared__ int cnt;
  __shared__ float red[256];
  if (t == 0) cnt = 0;
  __syncthreads();
  for (int i = t; i < Nsup; i += 256) {
    if (yhat[i] == c) {
      const int p = atomicAdd(&cnt, 1);
      if (p < MAXLIST) list[p] = i;
    }
  }
  __syncthreads();
  const int K = *Kp;
  const int n = min(cnt, MAXLIST);
  if (cnt <= K) {
    for (int j = t; j < n; j += 256) sel[j] = 1;
  } else {
    for (int j = t; j < n; j += 256) {
      const int si = list[j];
      const float ei = ent[si];
      int rank = 0;
      for (int l = 0; l < n; l++) {
        const int sl = list[l];
        const float el = ent[sl];
        rank += (el < ei || (el == ei && sl < si)) ? 1 : 0;
      }
      sel[j] = (rank < K) ? 1 : 0;
    }
  }
  __syncthreads();

  float a[8];
#pragma unroll
  for (int q = 0; q < 8; q++) a[q] = 0.f;
  for (int j = 0; j < n; j++) {
    if (!sel[j]) continue;
    const int si = list[j];
    const float* row = support_row(si, W, z, C) + t * 8;
    const float inv = 1.0f / fmaxf(norms[si], 1e-12f);
    const float4 p0 = *(const float4*)row;
    const float4 p1 = *(const float4*)(row + 4);
    a[0] = fmaf(p0.x, inv, a[0]); a[1] = fmaf(p0.y, inv, a[1]);
    a[2] = fmaf(p0.z, inv, a[2]); a[3] = fmaf(p0.w, inv, a[3]);
    a[4] = fmaf(p1.x, inv, a[4]); a[5] = fmaf(p1.y, inv, a[5]);
    a[6] = fmaf(p1.z, inv, a[6]); a[7] = fmaf(p1.w, inv, a[7]);
  }

  float ss = 0.f;
#pragma unroll
  for (int q = 0; q < 8; q++) ss = fmaf(a[q], a[q], ss);
  red[t] = ss;
  __syncthreads();
  for (int k = 128; k > 0; k >>= 1) {
    if (t < k) red[t] += red[t + k];
    __syncthreads();
  }
  const float invn = 1.0f / fmaxf(sqrtf(red[0]), 1e-12f);
  f16x8 o;
#pragma unroll
  for (int q = 0; q < 8; q++) o[q] = (f16)(a[q] * invn);
  *(f16x8*)dst = o;
}

// ---------------------------------------------------------------------------
// reduce_out: out[r][c] = Q0[r][c] + Q1[r][c], c < Ncols. One block per row.
// ---------------------------------------------------------------------------
__global__ __launch_bounds__(256) void reduce_out(const float* __restrict__ Q,
                                                  long partStride, int ldq,
                                                  float* __restrict__ out, int Ncols) {
  const int r = blockIdx.x;
  const float* q0 = Q + (size_t)r * ldq;
  const float* q1 = q0 + partStride;
  float* o = out + (size_t)r * Ncols;
  for (int c = threadIdx.x; c < Ncols; c += 256) o[c] = q0[c] + q1[c];
}

// ---------------------------------------------------------------------------
// Launch
// ---------------------------------------------------------------------------
extern "C" void kernel_launch(void* const* d_in, const int* in_sizes, int n_in,
                              void* d_out, int out_size, void* d_ws, size_t ws_size,
                              hipStream_t stream) {
  const float* z = (const float*)d_in[0];
  const float* W = (const float*)d_in[1];
  const int* Kp = (const int*)d_in[2];

  const int D = D_DIM;
  const int B = in_sizes[0] / D;   // 4096
  const int C = in_sizes[1] / D;   // 1000
  const int Nsup = C + B;          // 5096
  const int Mpad = (Nsup + TM - 1) / TM * TM;  // 5120
  const int Npad = (C + TN - 1) / TN * TN;     // 1024

  char* ws = (char*)d_ws;
  size_t off = 0;
  auto alloc = [&](size_t bytes) -> void* {
    void* p = ws + off;
    off += (bytes + 255) & ~(size_t)255;
    return p;
  };

  const long pStride1 = (long)Mpad * Npad;   // 5.24M floats per half
  const long pStride2 = (long)B * Npad;      // 4.19M floats per half

  f16*   suph  = (f16*)alloc((size_t)Mpad * D * sizeof(f16));          // ~21.0 MB
  f16*   wh    = (f16*)alloc((size_t)Npad * D * sizeof(f16));          // ~4.2 MB
  float* P     = (float*)alloc((size_t)2 * pStride1 * sizeof(float));  // ~41.9 MB
  float* ent   = (float*)alloc((size_t)Nsup * sizeof(float));
  int*   yhat  = (int*)alloc((size_t)Nsup * sizeof(int));
  float* norms = (float*)alloc((size_t)Nsup * sizeof(float));
  float* Q     = P;  // reuse: P fully consumed by row_stats before gemm2 writes Q
  (void)ws_size;

  // 1) f16 support matrix (padded) + norms
  prep_kernel<<<Mpad / 4, 256, 0, stream>>>(z, W, C, Nsup, suph, norms);

  // 2) logit partials: P[kz] = supports @ W^T over K-half kz (640 blocks)
  {
    dim3 grid(Mpad / TM, Npad / TN, 2);
    gemm_f16<<<grid, 256, 0, stream>>>(suph, suph, P, D, D / 2, pStride1, Npad);
  }

  // 3) block-per-row split-K merge + argmax/entropy + exact ambiguity repair
  row_stats<<<Nsup, 256, 0, stream>>>(P, pStride1, Npad, C, z, W, ent, yhat);

  // 4) per-class gather/select/accumulate/normalize -> wh[Npad, D] f16
  accum_kernel<<<Npad, 256, 0, stream>>>(z, W, C, Nsup, yhat, ent, norms, Kp, wh);

  // 5) output partials: Q[kz] = z @ weights^T over K-half kz (512 blocks)
  {
    dim3 grid(B / TM, Npad / TN, 2);
    gemm_f16<<<grid, 256, 0, stream>>>(suph + (size_t)C * D, wh, Q, D, D / 2, pStride2, Npad);
  }

  // 6) out = Q0 + Q1 (valid C cols only)
  reduce_out<<<B, 256, 0, stream>>>(Q, pStride2, Npad, (float*)d_out, C);
}